// Round 3
// baseline (6511.243 us; speedup 1.0000x reference)
//
#include <hip/hip_runtime.h>
#include <float.h>
#include <math.h>

#define H      1024
#define G4     4096
#define SLEN   128
#define VOUT   32000
#define NSTEP  51
#define EOS_ID 2
#define NB     256
#define BT     1024
#define NWAVES 16
#define GROWS  16      // G4/NB  gate rows per block
#define HROWS  4       // H/NB   ht_new rows per block
#define LROWS  125     // VOUT/NB logits rows per block
#define TOKS_OFF 51

// ws float-offsets (relative to wsf = d_ws + 4096 bytes)
#define WS_GATESA 0
#define WS_GATESB 4096
#define WS_SCORES 8192
#define WS_HTNG   8320
#define WS_PVAL   9344
#define WS_PIDX   9600
#define WS_MAXN   75776
#define WS_WLTB   131072   // ushort* region starts here (float offset)
#define WS_NEED_BYTES (4096ull + 131072ull*4ull + (unsigned long long)VOUT*H*2ull)

__device__ __forceinline__ float wredsum(float v){
  v += __shfl_xor(v, 32, 64);
  v += __shfl_xor(v, 16, 64);
  v += __shfl_xor(v,  8, 64);
  v += __shfl_xor(v,  4, 64);
  v += __shfl_xor(v,  2, 64);
  v += __shfl_xor(v,  1, 64);
  return v;
}
__device__ __forceinline__ float wredmax(float v){
  v = fmaxf(v, __shfl_xor(v, 32, 64));
  v = fmaxf(v, __shfl_xor(v, 16, 64));
  v = fmaxf(v, __shfl_xor(v,  8, 64));
  v = fmaxf(v, __shfl_xor(v,  4, 64));
  v = fmaxf(v, __shfl_xor(v,  2, 64));
  v = fmaxf(v, __shfl_xor(v,  1, 64));
  return v;
}
__device__ __forceinline__ float cload(const float* p){
  return __hip_atomic_load(p, __ATOMIC_RELAXED, __HIP_MEMORY_SCOPE_AGENT);
}
__device__ __forceinline__ int cloadi(const int* p){
  return __hip_atomic_load(p, __ATOMIC_RELAXED, __HIP_MEMORY_SCOPE_AGENT);
}
__device__ __forceinline__ void cstore(float* p, float v){
  __hip_atomic_store(p, v, __ATOMIC_RELAXED, __HIP_MEMORY_SCOPE_AGENT);
}
__device__ __forceinline__ void cstorei(int* p, int v){
  __hip_atomic_store(p, v, __ATOMIC_RELAXED, __HIP_MEMORY_SCOPE_AGENT);
}
__device__ __forceinline__ float sigm(float x){ return 1.0f/(1.0f+expf(-x)); }

// per-lane partial dot of a 1024-long row (16 elems/lane as 4x float4)
__device__ __forceinline__ float partdot(const float* __restrict__ a,
                                         const float* __restrict__ hp, int lane){
  const float4* a4 = (const float4*)a;
  const float4* h4 = (const float4*)hp;
  float s = 0.f;
#pragma unroll
  for(int k=0;k<4;k++){
    float4 x = a4[lane + 64*k];
    float4 y = h4[lane + 64*k];
    s = fmaf(x.x,y.x,s); s = fmaf(x.y,y.y,s);
    s = fmaf(x.z,y.z,s); s = fmaf(x.w,y.w,s);
  }
  return s;
}

__device__ __forceinline__ float bflo(unsigned u){ return __uint_as_float(u<<16); }
__device__ __forceinline__ float bfhi(unsigned u){ return __uint_as_float(u & 0xffff0000u); }
__device__ __forceinline__ float dot8bf(uint4 q, const float* h, float acc){
  acc = fmaf(bflo(q.x), h[0], acc); acc = fmaf(bfhi(q.x), h[1], acc);
  acc = fmaf(bflo(q.y), h[2], acc); acc = fmaf(bfhi(q.y), h[3], acc);
  acc = fmaf(bflo(q.z), h[4], acc); acc = fmaf(bfhi(q.z), h[5], acc);
  acc = fmaf(bflo(q.w), h[6], acc); acc = fmaf(bfhi(q.w), h[7], acc);
  return acc;
}
// RNE fp32->bf16
__device__ __forceinline__ unsigned short f2bf(float x){
  unsigned u = __float_as_uint(x);
  unsigned r = (u + 0x7fffu + ((u>>16)&1u)) >> 16;
  return (unsigned short)r;
}

// ---- one-time converter: W_lt fp32 -> bf16 in ws, plus max row L2-norm ----
extern "C" __global__ void __launch_bounds__(256)
conv_wlt(const float* __restrict__ W, unsigned short* __restrict__ o,
         unsigned* __restrict__ maxn){
  const int wv = threadIdx.x >> 6, lane = threadIdx.x & 63;
  float best = 0.f;
  for(int rr=0; rr<16; rr++){
    const int row = blockIdx.x*64 + rr*4 + wv;
    const float4* p = (const float4*)(W + (size_t)row*H) + 4*lane;
    float4 f0=p[0], f1=p[1], f2=p[2], f3=p[3];
    float sq;
    sq  = f0.x*f0.x; sq = fmaf(f0.y,f0.y,sq); sq = fmaf(f0.z,f0.z,sq); sq = fmaf(f0.w,f0.w,sq);
    sq = fmaf(f1.x,f1.x,sq); sq = fmaf(f1.y,f1.y,sq); sq = fmaf(f1.z,f1.z,sq); sq = fmaf(f1.w,f1.w,sq);
    sq = fmaf(f2.x,f2.x,sq); sq = fmaf(f2.y,f2.y,sq); sq = fmaf(f2.z,f2.z,sq); sq = fmaf(f2.w,f2.w,sq);
    sq = fmaf(f3.x,f3.x,sq); sq = fmaf(f3.y,f3.y,sq); sq = fmaf(f3.z,f3.z,sq); sq = fmaf(f3.w,f3.w,sq);
    union { unsigned short us[16]; uint4 q[2]; } u;
    u.us[0]=f2bf(f0.x); u.us[1]=f2bf(f0.y); u.us[2]=f2bf(f0.z); u.us[3]=f2bf(f0.w);
    u.us[4]=f2bf(f1.x); u.us[5]=f2bf(f1.y); u.us[6]=f2bf(f1.z); u.us[7]=f2bf(f1.w);
    u.us[8]=f2bf(f2.x); u.us[9]=f2bf(f2.y); u.us[10]=f2bf(f2.z); u.us[11]=f2bf(f2.w);
    u.us[12]=f2bf(f3.x); u.us[13]=f2bf(f3.y); u.us[14]=f2bf(f3.z); u.us[15]=f2bf(f3.w);
    uint4* op = (uint4*)(o + (size_t)row*H) + 2*lane;
    op[0]=u.q[0]; op[1]=u.q[1];
    sq = wredsum(sq);
    if(lane==0) best = fmaxf(best, sq);
  }
  if(lane==0) atomicMax(maxn, __float_as_uint(sqrtf(best)));
}

template<bool BF>
__global__ void __launch_bounds__(BT)
nmt_kernel(const int* __restrict__ src_ids,
           const float* __restrict__ embed_input,
           const float* __restrict__ W_ih_e, const float* __restrict__ W_hh_e,
           const float* __restrict__ b_ih_e, const float* __restrict__ b_hh_e,
           const float* __restrict__ W_li,  const float* __restrict__ b_li,
           const float* __restrict__ embed_target,
           const float* __restrict__ W_ih_d, const float* __restrict__ W_hh_d,
           const float* __restrict__ b_ih_d, const float* __restrict__ b_hh_d,
           const float* __restrict__ W_lt,  const float* __restrict__ b_lt,
           const float* __restrict__ W_tl,  const float* __restrict__ b_tl,
           float* __restrict__ out, float* __restrict__ ws,
           unsigned* __restrict__ counters,
           const unsigned short* __restrict__ wltb)
{
  const int tid  = threadIdx.x;
  const int b    = blockIdx.x;
  const int w    = tid >> 6;
  const int lane = tid & 63;

  float* gatesA  = ws + WS_GATESA;
  float* gatesB  = ws + WS_GATESB;
  float* scoresg = ws + WS_SCORES;
  float* htng    = ws + WS_HTNG;
  float* pval    = ws + WS_PVAL;
  int*   pidx    = (int*)(ws + WS_PIDX);

  __shared__ __align__(16) float hbuf[2][H];
  __shared__ __align__(16) float c_lds[H];
  __shared__ __align__(16) float hsrow[H];
  __shared__ __align__(16) float htn_lds[H];
  __shared__ __align__(16) float xenc[SLEN][NWAVES];
  __shared__ __align__(16) float Mloc[HROWS][SLEN];
  __shared__ __align__(16) float sraw[SLEN];
  __shared__ __align__(16) float sc_e[SLEN];
  __shared__ __align__(16) float vloc[128];
  __shared__ int   rlist[128];
  __shared__ float wred2[4];
  __shared__ float redv[NWAVES];
  __shared__ int   redi[NWAVES];
  __shared__ float gwhh_l[NWAVES];
  __shared__ float pv_l[NB];
  __shared__ int   pi_l[NB];
  __shared__ int   toks_lds[SLEN];
  __shared__ int   wid_sh, done_sh;
  __shared__ float B_sh;
  __shared__ int   rcnt_sh;

  // guarded max-row-norm of W_lt (garbage/zero -> huge bound -> full fp32 path)
  float mnorm = 0.f;
  if(BF){
    mnorm = __uint_as_float((unsigned)cloadi((const int*)(ws + WS_MAXN)));
    if(!(mnorm > 1e-6f && mnorm < 1e6f)) mnorm = 1e6f;
  }

  int pc = 0;
#define GRID_BARRIER() do{                                                     \
    __syncthreads();                                                           \
    if(tid==0){                                                                \
      __hip_atomic_fetch_add(&counters[pc], 1u, __ATOMIC_RELEASE,              \
                             __HIP_MEMORY_SCOPE_AGENT);                        \
      while(__hip_atomic_load(&counters[pc], __ATOMIC_RELAXED,                 \
                              __HIP_MEMORY_SCOPE_AGENT) < (unsigned)NB){       \
        __builtin_amdgcn_s_sleep(1);                                           \
      }                                                                        \
    }                                                                          \
    pc++;                                                                      \
    __syncthreads();                                                           \
    asm volatile("" ::: "memory");                                             \
  }while(0)

  // ---- init ----
  hbuf[0][tid] = 0.f;
  c_lds[tid]   = 0.f;
  if (tid < SLEN) toks_lds[tid] = src_ids[tid];
  __syncthreads();

  // ---- Xenc precompute: xenc[t][w] = W_ih_e[row].x_t + b_ih_e + b_hh_e ----
  {
    const int row = b*GROWS + w;
    const float4* wr = (const float4*)(W_ih_e + (size_t)row*H);
    float4 w0=wr[lane], w1=wr[lane+64], w2=wr[lane+128], w3=wr[lane+192];
    const float bias = b_ih_e[row] + b_hh_e[row];
    for(int t=0;t<SLEN;t++){
      const float4* xr = (const float4*)(embed_input + (size_t)toks_lds[t]*H);
      float4 x0=xr[lane], x1=xr[lane+64], x2=xr[lane+128], x3=xr[lane+192];
      float s;
      s = w0.x*x0.x;        s = fmaf(w0.y,x0.y,s); s = fmaf(w0.z,x0.z,s); s = fmaf(w0.w,x0.w,s);
      s = fmaf(w1.x,x1.x,s); s = fmaf(w1.y,x1.y,s); s = fmaf(w1.z,x1.z,s); s = fmaf(w1.w,x1.w,s);
      s = fmaf(w2.x,x2.x,s); s = fmaf(w2.y,x2.y,s); s = fmaf(w2.z,x2.z,s); s = fmaf(w2.w,x2.w,s);
      s = fmaf(w3.x,x3.x,s); s = fmaf(w3.y,x3.y,s); s = fmaf(w3.z,x3.z,s); s = fmaf(w3.w,x3.w,s);
      s = wredsum(s);
      if(lane==0) xenc[t][w] = s + bias;
    }
  }
  __syncthreads();

  // ---- encoder: 128 steps, 1 grid barrier each ----
  for(int t=0;t<SLEN;t++){
    float* gw = (t&1) ? gatesB : gatesA;
    {
      const int row = b*GROWS + w;
      float s = partdot(W_hh_e + (size_t)row*H, hbuf[0], lane);
      s = wredsum(s);
      if(lane==0) cstore(&gw[row], s + xenc[t][w]);
    }
    GRID_BARRIER();
    {
      const int d = tid;
      float gi = cload(&gw[d]);
      float gf = cload(&gw[d+H]);
      float gg = cload(&gw[d+2*H]);
      float go = cload(&gw[d+3*H]);
      float ii=sigm(gi), ff=sigm(gf), g2=tanhf(gg), oo=sigm(go);
      float c2 = fmaf(ff, c_lds[d], ii*g2);
      c_lds[d] = c2;
      float h2 = oo*tanhf(c2);
      hbuf[0][d] = h2;
      if (b==t) hsrow[d] = h2;
    }
    __syncthreads();
    if (w < HROWS){
      const int r = b*HROWS + w;
      float s = partdot(W_tl + (size_t)r*2*H, hbuf[0], lane);
      s = wredsum(s);
      if(lane==0) Mloc[w][t] = s;
    }
    __syncthreads();
  }

  // ---- wid0 = argmax(W_li . hs + b_li)  (round-1 verbatim) ----
  {
    float bestv=-FLT_MAX; int besti=0;
    for(int j=w; j<LROWS; j+=NWAVES){
      const int r = b*LROWS + j;
      float s = wredsum(partdot(W_li + (size_t)r*H, hbuf[0], lane));
      if(lane==0){
        float v = s + b_li[r];
        if(v>bestv){ bestv=v; besti=r; }
      }
    }
    if(lane==0){ redv[w]=bestv; redi[w]=besti; }
    __syncthreads();
    if(tid==0){
      float bv=redv[0]; int bi=redi[0];
      for(int i=1;i<NWAVES;i++)
        if(redv[i]>bv || (redv[i]==bv && redi[i]<bi)){ bv=redv[i]; bi=redi[i]; }
      cstore(&pval[b], bv); cstorei(&pidx[b], bi);
    }
  }
  GRID_BARRIER();
  {
    if(tid<NB){ pv_l[tid]=cload(&pval[tid]); pi_l[tid]=cloadi(&pidx[tid]); }
    __syncthreads();
    if(tid==0){
      float bv=pv_l[0]; int bi=pi_l[0];
      for(int i=1;i<NB;i++)
        if(pv_l[i]>bv || (pv_l[i]==bv && pi_l[i]<bi)){ bv=pv_l[i]; bi=pi_l[i]; }
      wid_sh = bi;
      done_sh = (bi==EOS_ID) ? 1 : 0;
    }
    __syncthreads();
  }

  // ---- first decoder cell ----
  {
    const int row = b*GROWS + w;
    const float* tk = embed_target + (size_t)wid_sh*H;
    float s = partdot(W_ih_d + (size_t)row*H, tk, lane)
            + partdot(W_hh_d + (size_t)row*H, hbuf[0], lane);
    s = wredsum(s);
    if(lane==0) cstore(&gatesA[row], s + b_ih_d[row] + b_hh_d[row]);
  }
  GRID_BARRIER();
  {
    const int d = tid;
    float gi=cload(&gatesA[d]), gf=cload(&gatesA[d+H]),
          gg=cload(&gatesA[d+2*H]), go=cload(&gatesA[d+3*H]);
    float ii=sigm(gi), ff=sigm(gf), g2=tanhf(gg), oo=sigm(go);
    float c2=fmaf(ff, c_lds[d], ii*g2);
    c_lds[d]=c2;
    hbuf[1][d]=oo*tanhf(c2);
  }
  __syncthreads();
  if(b<SLEN && w==0){
    float s = wredsum(partdot(hsrow, hbuf[1], lane));
    if(lane==0) cstore(&scoresg[b], s);
  }
  {
    const int row=b*GROWS+w;
    float s=wredsum(partdot(W_hh_d + (size_t)row*H, hbuf[1], lane));
    if(lane==0) gwhh_l[w]=s;
  }
  GRID_BARRIER();

  // ---- decode: 51 steps, 2 barriers each ----
  int cur = 1;
  for(int k=0;k<NSTEP;k++){
    float* hk = hbuf[cur];
    float* hn = hbuf[cur^1];
    // -------- P1 (round-1 verbatim) --------
    if(k>0){
      if(tid<NB){ pv_l[tid]=cload(&pval[tid]); pi_l[tid]=cloadi(&pidx[tid]); }
      __syncthreads();
      if(tid==0){
        float bv=pv_l[0]; int bi=pi_l[0];
        for(int i=1;i<NB;i++)
          if(pv_l[i]>bv || (pv_l[i]==bv && pi_l[i]<bi)){ bv=pv_l[i]; bi=pi_l[i]; }
        int iseos=(bi==EOS_ID)?1:0;
        int outtok=(done_sh|iseos)?-1:bi;
        if(b==0) out[k-1]=(float)outtok;
        done_sh |= iseos;
        wid_sh = bi;
      }
      __syncthreads();
    }
    // softmax over 128 scores
    if(tid<SLEN) sraw[tid]=cload(&scoresg[tid]);
    __syncthreads();
    if(tid<SLEN){
      float m = wredmax(sraw[tid]);
      if(lane==0) wred2[w]=m;
    }
    __syncthreads();
    if(tid<SLEN){
      float mx=fmaxf(wred2[0],wred2[1]);
      float e=expf(sraw[tid]-mx);
      sc_e[tid]=e;
      float z=wredsum(e);
      if(lane==0) wred2[2+w]=z;
    }
    __syncthreads();
    // decoder LSTM gates
    {
      const int row=b*GROWS+w;
      const float* tk=embed_target + (size_t)wid_sh*H;
      float s=wredsum(partdot(W_ih_d + (size_t)row*H, tk, lane));
      if(lane==0) cstore(&gatesA[row], s + gwhh_l[w] + b_ih_d[row] + b_hh_d[row]);
    }
    // ht_new rows via M-trick
    if(w<HROWS){
      const int r=b*HROWS+w;
      float invZ=1.f/(wred2[2]+wred2[3]);
      float att=fmaf(sc_e[2*lane],Mloc[w][2*lane], sc_e[2*lane+1]*Mloc[w][2*lane+1]);
      float s=partdot(W_tl + (size_t)r*2*H + H, hk, lane);
      float tot=wredsum(fmaf(att,invZ,s));
      if(lane==0) cstore(&htng[r], tanhf(tot + b_tl[r]));
    }
    GRID_BARRIER();
    // -------- P2 --------
    {
      htn_lds[tid]=cload(&htng[tid]);
      const int d=tid;
      float gi=cload(&gatesA[d]), gf=cload(&gatesA[d+H]),
            gg=cload(&gatesA[d+2*H]), go=cload(&gatesA[d+3*H]);
      float ii=sigm(gi), ff=sigm(gf), g2=tanhf(gg), oo=sigm(go);
      float c2=fmaf(ff,c_lds[d],ii*g2);
      c_lds[d]=c2;
      hn[d]=oo*tanhf(c2);
    }
    __syncthreads();
    if(BF){
      // ||h||^2 partials; reset rescue counter
      {
        float x = htn_lds[tid];
        float ss = wredsum(x*x);
        if(lane==0) redv[w]=ss;
        if(tid==0) rcnt_sh=0;
      }
      __syncthreads();              // S1
      if(tid==0){
        float t2=0.f;
        for(int i=0;i<NWAVES;i++) t2+=redv[i];
        float Bv = 0.015625f * mnorm * sqrtf(t2) + 0.01f;   // 4x slack + abs
        if(!(Bv >= 0.01f && Bv < 1e6f)) Bv = 3.0e38f;       // NaN/garbage -> screen all
        B_sh = Bv;
      }
      // bf16 screening matvec, 8 rows in flight per wave
      {
        float hreg[16];
#pragma unroll
        for(int i=0;i<16;i++) hreg[i]=htn_lds[16*lane+i];
        const size_t rbase = (size_t)b*LROWS;
        uint4 qa[8], qb[8];
        int jj[8]; bool vl[8];
#pragma unroll
        for(int t=0;t<8;t++){
          int j = w + NWAVES*t;
          jj[t]=j; vl[t]=(j<LROWS);
          size_t r = rbase + (vl[t]? j : 0);
          const uint4* p = (const uint4*)(wltb + r*H) + 2*lane;
          qa[t]=p[0]; qb[t]=p[1];
        }
        float s[8];
#pragma unroll
        for(int t=0;t<8;t++){
          float acc=0.f;
          acc = dot8bf(qa[t], hreg, acc);
          acc = dot8bf(qb[t], hreg+8, acc);
          s[t]=acc;
        }
#pragma unroll
        for(int t=0;t<8;t++) s[t]=wredsum(s[t]);
        if(lane==0){
#pragma unroll
          for(int t=0;t<8;t++) if(vl[t]) vloc[jj[t]] = s[t] + b_lt[rbase+jj[t]];
        }
      }
      __syncthreads();              // S2: vloc + B_sh visible
      // logits out (bf16-accurate, coalesced) + block-local bf16 max
      {
        const size_t obase = TOKS_OFF + (size_t)k*VOUT + (size_t)b*LROWS;
        if(tid<LROWS) out[obase + tid] = vloc[tid];
        float mv = (tid<LROWS)? vloc[tid] : -FLT_MAX;
        if(tid<128){
          float m = wredmax(mv);
          if(lane==0) wred2[w]=m;
        }
      }
      __syncthreads();              // S3
      {
        float mx = fmaxf(wred2[0], wred2[1]);
        if(tid<LROWS && vloc[tid] >= mx - 2.0f*B_sh){
          int pos = atomicAdd(&rcnt_sh,1);
          rlist[pos] = tid;         // pos < LROWS always
        }
      }
      __syncthreads();              // S4: rlist ready
      // fp32 re-dot of screened rows (bitwise-identical to round-1 values)
      {
        float bestv=-FLT_MAX; int besti=0x7fffffff;
        const int nr = rcnt_sh;
        for(int s2=w; s2<nr; s2+=NWAVES){
          const int r = b*LROWS + rlist[s2];
          float f = wredsum(partdot(W_lt + (size_t)r*H, htn_lds, lane)) + b_lt[r];
          if(lane==0){
            if(f>bestv || (f==bestv && r<besti)){ bestv=f; besti=r; }
          }
        }
        if(lane==0){ redv[w]=bestv; redi[w]=besti; }
      }
    } else {
      float bestv=-FLT_MAX; int besti=0;
      const size_t obase = TOKS_OFF + (size_t)k*VOUT;
      for(int j=w;j<LROWS;j+=NWAVES){
        const int r=b*LROWS+j;
        float s=wredsum(partdot(W_lt + (size_t)r*H, htn_lds, lane));
        if(lane==0){
          float v=s+b_lt[r];
          out[obase + r]=v;
          if(v>bestv){bestv=v;besti=r;}
        }
      }
      if(lane==0){ redv[w]=bestv; redi[w]=besti; }
    }
    if(b<SLEN && w==0){
      float s=wredsum(partdot(hsrow, hn, lane));
      if(lane==0) cstore(&scoresg[b], s);
    }
    {
      const int row=b*GROWS+w;
      float s=wredsum(partdot(W_hh_d + (size_t)row*H, hn, lane));
      if(lane==0) gwhh_l[w]=s;
    }
    __syncthreads();
    if(tid==0){
      float bv=redv[0]; int bi=redi[0];
      for(int i=1;i<NWAVES;i++)
        if(redv[i]>bv || (redv[i]==bv && redi[i]<bi)){ bv=redv[i]; bi=redi[i]; }
      cstore(&pval[b], bv); cstorei(&pidx[b], bi);
    }
    GRID_BARRIER();
    cur ^= 1;
  }

  // ---- epilogue: last token (round-1 verbatim) ----
  if(b==0){
    if(tid<NB){ pv_l[tid]=cload(&pval[tid]); pi_l[tid]=cloadi(&pidx[tid]); }
    __syncthreads();
    if(tid==0){
      float bv=pv_l[0]; int bi=pi_l[0];
      for(int i=1;i<NB;i++)
        if(pv_l[i]>bv || (pv_l[i]==bv && pi_l[i]<bi)){ bv=pv_l[i]; bi=pi_l[i]; }
      int iseos=(bi==EOS_ID)?1:0;
      out[NSTEP-1]=(float)((done_sh|iseos)?-1:bi);
    }
  }
#undef GRID_BARRIER
}

extern "C" void kernel_launch(void* const* d_in, const int* in_sizes, int n_in,
                              void* d_out, int out_size, void* d_ws, size_t ws_size,
                              hipStream_t stream) {
  const int*   src_ids      = (const int*)  d_in[0];
  const float* embed_input  = (const float*)d_in[1];
  const float* W_ih_e       = (const float*)d_in[2];
  const float* W_hh_e       = (const float*)d_in[3];
  const float* b_ih_e       = (const float*)d_in[4];
  const float* b_hh_e       = (const float*)d_in[5];
  const float* W_li         = (const float*)d_in[6];
  const float* b_li         = (const float*)d_in[7];
  const float* embed_target = (const float*)d_in[8];
  const float* W_ih_d       = (const float*)d_in[9];
  const float* W_hh_d       = (const float*)d_in[10];
  const float* b_ih_d       = (const float*)d_in[11];
  const float* b_hh_d       = (const float*)d_in[12];
  const float* W_lt         = (const float*)d_in[13];
  const float* b_lt         = (const float*)d_in[14];
  const float* W_tl         = (const float*)d_in[15];
  const float* b_tl         = (const float*)d_in[16];
  float*       out          = (float*)d_out;
  unsigned*    counters     = (unsigned*)d_ws;
  float*       wsf          = (float*)d_ws + 1024;   // data after 4KB counter area

  const bool use_bf = (ws_size >= WS_NEED_BYTES + 65536ull);
  unsigned short* wltb = use_bf ? (unsigned short*)(wsf + WS_WLTB) : nullptr;

  hipMemsetAsync(d_ws, 0, 4096, stream);
  if(use_bf){
    hipMemsetAsync((void*)((char*)d_ws + 4096 + (size_t)WS_MAXN*4), 0, 4, stream);
    conv_wlt<<<dim3(VOUT/64), dim3(256), 0, stream>>>(
        W_lt, wltb, (unsigned*)(wsf + WS_MAXN));
  }

  const unsigned short* wltb_c = wltb;
  void* args[] = {
    (void*)&src_ids, (void*)&embed_input,
    (void*)&W_ih_e, (void*)&W_hh_e, (void*)&b_ih_e, (void*)&b_hh_e,
    (void*)&W_li, (void*)&b_li, (void*)&embed_target,
    (void*)&W_ih_d, (void*)&W_hh_d, (void*)&b_ih_d, (void*)&b_hh_d,
    (void*)&W_lt, (void*)&b_lt, (void*)&W_tl, (void*)&b_tl,
    (void*)&out, (void*)&wsf, (void*)&counters, (void*)&wltb_c
  };

  hipError_t err;
  if(use_bf){
    err = hipLaunchCooperativeKernel((const void*)nmt_kernel<true>,
                                     dim3(NB), dim3(BT), args, 0, stream);
    if (err != hipSuccess) {
      nmt_kernel<true><<<dim3(NB), dim3(BT), 0, stream>>>(
          src_ids, embed_input, W_ih_e, W_hh_e, b_ih_e, b_hh_e,
          W_li, b_li, embed_target, W_ih_d, W_hh_d, b_ih_d, b_hh_d,
          W_lt, b_lt, W_tl, b_tl, out, wsf, counters, wltb_c);
    }
  } else {
    err = hipLaunchCooperativeKernel((const void*)nmt_kernel<false>,
                                     dim3(NB), dim3(BT), args, 0, stream);
    if (err != hipSuccess) {
      nmt_kernel<false><<<dim3(NB), dim3(BT), 0, stream>>>(
          src_ids, embed_input, W_ih_e, W_hh_e, b_ih_e, b_hh_e,
          W_li, b_li, embed_target, W_ih_d, W_hh_d, b_ih_d, b_hh_d,
          W_lt, b_lt, W_tl, b_tl, out, wsf, counters, wltb_c);
    }
  }
}

// Round 4
// 4132.332 us; speedup vs baseline: 1.5757x; 1.5757x over previous
//
#include <hip/hip_runtime.h>
#include <float.h>
#include <math.h>

#define H      1024
#define G4     4096
#define SLEN   128
#define VOUT   32000
#define NSTEP  51
#define EOS_ID 2
#define NB     256
#define BT     1024
#define NWAVES 16
#define GROWS  16      // G4/NB  gate rows per block
#define HROWS  4       // H/NB   ht_new rows per block
#define LROWS  125     // VOUT/NB logits rows per block
#define TOKS_OFF 51
#define QTAB_BYTES (LROWS*H)   // 128000 B dynamic LDS: int8 W_lt rows

// ws float-offsets (relative to wsf = d_ws + 4096 bytes) — round-1 layout
#define WS_GATESA 0
#define WS_GATESB 4096
#define WS_SCORES 8192
#define WS_HTNG   8320
#define WS_PVAL   9344
#define WS_PIDX   9600

__device__ __forceinline__ float wredsum(float v){
  v += __shfl_xor(v, 32, 64);
  v += __shfl_xor(v, 16, 64);
  v += __shfl_xor(v,  8, 64);
  v += __shfl_xor(v,  4, 64);
  v += __shfl_xor(v,  2, 64);
  v += __shfl_xor(v,  1, 64);
  return v;
}
__device__ __forceinline__ float wredmax(float v){
  v = fmaxf(v, __shfl_xor(v, 32, 64));
  v = fmaxf(v, __shfl_xor(v, 16, 64));
  v = fmaxf(v, __shfl_xor(v,  8, 64));
  v = fmaxf(v, __shfl_xor(v,  4, 64));
  v = fmaxf(v, __shfl_xor(v,  2, 64));
  v = fmaxf(v, __shfl_xor(v,  1, 64));
  return v;
}
__device__ __forceinline__ float cload(const float* p){
  return __hip_atomic_load(p, __ATOMIC_RELAXED, __HIP_MEMORY_SCOPE_AGENT);
}
__device__ __forceinline__ int cloadi(const int* p){
  return __hip_atomic_load(p, __ATOMIC_RELAXED, __HIP_MEMORY_SCOPE_AGENT);
}
__device__ __forceinline__ void cstore(float* p, float v){
  __hip_atomic_store(p, v, __ATOMIC_RELAXED, __HIP_MEMORY_SCOPE_AGENT);
}
__device__ __forceinline__ void cstorei(int* p, int v){
  __hip_atomic_store(p, v, __ATOMIC_RELAXED, __HIP_MEMORY_SCOPE_AGENT);
}
__device__ __forceinline__ float sigm(float x){ return 1.0f/(1.0f+expf(-x)); }

// per-lane partial dot of a 1024-long row (16 elems/lane as 4x float4)
__device__ __forceinline__ float partdot(const float* __restrict__ a,
                                         const float* __restrict__ hp, int lane){
  const float4* a4 = (const float4*)a;
  const float4* h4 = (const float4*)hp;
  float s = 0.f;
#pragma unroll
  for(int k=0;k<4;k++){
    float4 x = a4[lane + 64*k];
    float4 y = h4[lane + 64*k];
    s = fmaf(x.x,y.x,s); s = fmaf(x.y,y.y,s);
    s = fmaf(x.z,y.z,s); s = fmaf(x.w,y.w,s);
  }
  return s;
}

// int8x4 dot with float4 (little-endian byte k = element k)
__device__ __forceinline__ float dotq(unsigned u, float4 hv, float acc){
  acc = fmaf((float)((int)(u<<24)>>24), hv.x, acc);
  acc = fmaf((float)((int)(u<<16)>>24), hv.y, acc);
  acc = fmaf((float)((int)(u<< 8)>>24), hv.z, acc);
  acc = fmaf((float)((int) u     >>24), hv.w, acc);
  return acc;
}

extern "C" __global__ void __launch_bounds__(BT)
nmt_kernel(const int* __restrict__ src_ids,
           const float* __restrict__ embed_input,
           const float* __restrict__ W_ih_e, const float* __restrict__ W_hh_e,
           const float* __restrict__ b_ih_e, const float* __restrict__ b_hh_e,
           const float* __restrict__ W_li,  const float* __restrict__ b_li,
           const float* __restrict__ embed_target,
           const float* __restrict__ W_ih_d, const float* __restrict__ W_hh_d,
           const float* __restrict__ b_ih_d, const float* __restrict__ b_hh_d,
           const float* __restrict__ W_lt,  const float* __restrict__ b_lt,
           const float* __restrict__ W_tl,  const float* __restrict__ b_tl,
           float* __restrict__ out, float* __restrict__ ws,
           unsigned* __restrict__ counters)
{
  const int tid  = threadIdx.x;
  const int b    = blockIdx.x;
  const int w    = tid >> 6;
  const int lane = tid & 63;

  float* gatesA  = ws + WS_GATESA;
  float* gatesB  = ws + WS_GATESB;
  float* scoresg = ws + WS_SCORES;
  float* htng    = ws + WS_HTNG;
  float* pval    = ws + WS_PVAL;
  int*   pidx    = (int*)(ws + WS_PIDX);

  extern __shared__ __align__(16) char qmem[];       // 128000 B int8 table
  uint4* qtab = (uint4*)qmem;                        // row j: qtab[j*64 + lane]

  __shared__ __align__(16) float hbuf[2][H];
  __shared__ __align__(16) float c_lds[H];
  __shared__ __align__(16) float hsrow[H];
  __shared__ __align__(16) float htn_lds[H];
  __shared__ __align__(16) float xenc[SLEN][NWAVES];
  __shared__ __align__(16) float Mloc[HROWS][SLEN];
  __shared__ __align__(16) float sraw[SLEN];
  __shared__ __align__(16) float vloc[128];
  __shared__ __align__(16) float qrho[128];
  __shared__ __align__(16) float qinv[128];
  __shared__ int   rlist[128];
  __shared__ float hn2[NWAVES];
  __shared__ float wred2[4];
  __shared__ float redv[NWAVES];
  __shared__ int   redi[NWAVES];
  __shared__ float gwhh_l[NWAVES];
  __shared__ int   wid_sh, done_sh;
  __shared__ float e_sh, rhomax_sh;
  __shared__ int   rcnt_sh;

  int pc = 0;
#define GRID_BARRIER() do{                                                     \
    __syncthreads();                                                           \
    if(tid==0){                                                                \
      __hip_atomic_fetch_add(&counters[pc], 1u, __ATOMIC_RELEASE,              \
                             __HIP_MEMORY_SCOPE_AGENT);                        \
      while(__hip_atomic_load(&counters[pc], __ATOMIC_RELAXED,                 \
                              __HIP_MEMORY_SCOPE_AGENT) < (unsigned)NB){       \
        __builtin_amdgcn_s_sleep(1);                                           \
      }                                                                        \
    }                                                                          \
    pc++;                                                                      \
    __syncthreads();                                                           \
    asm volatile("" ::: "memory");                                             \
  }while(0)

// wave-parallel argmax over 256 global (pval,pidx) entries -> redv/redi[0..3]
#define GARGMAX()  do{                                                         \
    if(w<4){                                                                   \
      float v = cload(&pval[(w<<6)+lane]);                                     \
      int   i = cloadi(&pidx[(w<<6)+lane]);                                    \
      _Pragma("unroll")                                                        \
      for(int dd=32; dd>=1; dd>>=1){                                           \
        float ov=__shfl_xor(v,dd,64); int oi=__shfl_xor(i,dd,64);              \
        if(ov>v || (ov==v && oi<i)){ v=ov; i=oi; }                             \
      }                                                                        \
      if(lane==0){ redv[w]=v; redi[w]=i; }                                     \
    }                                                                          \
  }while(0)

  // ---- init ----
  hbuf[0][tid] = 0.f;
  c_lds[tid]   = 0.f;
  __syncthreads();

  // ---- Xenc precompute: xenc[t][w] = W_ih_e[row].x_t + b_ih_e + b_hh_e ----
  {
    const int row = b*GROWS + w;
    const float4* wr = (const float4*)(W_ih_e + (size_t)row*H);
    float4 w0=wr[lane], w1=wr[lane+64], w2=wr[lane+128], w3=wr[lane+192];
    const float bias = b_ih_e[row] + b_hh_e[row];
    for(int t=0;t<SLEN;t++){
      const float4* xr = (const float4*)(embed_input + (size_t)src_ids[t]*H);
      float4 x0=xr[lane], x1=xr[lane+64], x2=xr[lane+128], x3=xr[lane+192];
      float s;
      s = w0.x*x0.x;        s = fmaf(w0.y,x0.y,s); s = fmaf(w0.z,x0.z,s); s = fmaf(w0.w,x0.w,s);
      s = fmaf(w1.x,x1.x,s); s = fmaf(w1.y,x1.y,s); s = fmaf(w1.z,x1.z,s); s = fmaf(w1.w,x1.w,s);
      s = fmaf(w2.x,x2.x,s); s = fmaf(w2.y,x2.y,s); s = fmaf(w2.z,x2.z,s); s = fmaf(w2.w,x2.w,s);
      s = fmaf(w3.x,x3.x,s); s = fmaf(w3.y,x3.y,s); s = fmaf(w3.w,x3.w,s); s = fmaf(w3.z,x3.z,s);
      s = wredsum(s);
      if(lane==0) xenc[t][w] = s + bias;
    }
  }
  __syncthreads();

  // ---- encoder: 128 steps, 1 grid barrier each ----
  for(int t=0;t<SLEN;t++){
    float* gw = (t&1) ? gatesB : gatesA;
    {
      const int row = b*GROWS + w;
      float s = partdot(W_hh_e + (size_t)row*H, hbuf[0], lane);
      s = wredsum(s);
      if(lane==0) cstore(&gw[row], s + xenc[t][w]);
    }
    GRID_BARRIER();
    {
      const int d = tid;
      float gi = cload(&gw[d]);
      float gf = cload(&gw[d+H]);
      float gg = cload(&gw[d+2*H]);
      float go = cload(&gw[d+3*H]);
      float ii=sigm(gi), ff=sigm(gf), g2=tanhf(gg), oo=sigm(go);
      float c2 = fmaf(ff, c_lds[d], ii*g2);
      c_lds[d] = c2;
      float h2 = oo*tanhf(c2);
      hbuf[0][d] = h2;
      if (b==t) hsrow[d] = h2;
    }
    __syncthreads();
    if (w < HROWS){
      const int r = b*HROWS + w;
      float s = partdot(W_tl + (size_t)r*2*H, hbuf[0], lane);
      s = wredsum(s);
      if(lane==0) Mloc[w][t] = s;
    }
    __syncthreads();
  }

  // ---- one-time: quantize this block's 125 W_lt rows into LDS (int8) ----
  // exact residual norm rho_r = ||w_r - q_r*invs||_2  (Cauchy-Schwarz screen)
  {
    const int rbase = b*LROWS;
#pragma unroll
    for(int t=0;t<8;t++){
      const int j = w + NWAVES*t;
      if(j < LROWS){
        const float4* wr = (const float4*)(W_lt + (size_t)(rbase+j)*H);
        float4 f0=wr[4*lane], f1=wr[4*lane+1], f2=wr[4*lane+2], f3=wr[4*lane+3];
        float m;
        m = fmaxf(fabsf(f0.x),fabsf(f0.y)); m=fmaxf(m,fmaxf(fabsf(f0.z),fabsf(f0.w)));
        m = fmaxf(m,fmaxf(fabsf(f1.x),fabsf(f1.y))); m=fmaxf(m,fmaxf(fabsf(f1.z),fabsf(f1.w)));
        m = fmaxf(m,fmaxf(fabsf(f2.x),fabsf(f2.y))); m=fmaxf(m,fmaxf(fabsf(f2.z),fabsf(f2.w)));
        m = fmaxf(m,fmaxf(fabsf(f3.x),fabsf(f3.y))); m=fmaxf(m,fmaxf(fabsf(f3.z),fabsf(f3.w)));
        m = wredmax(m);
        const float s    = (m>1e-30f) ? 127.0f/m : 0.f;
        const float invs = (m>1e-30f) ? m*(1.0f/127.0f) : 0.f;
        float rsq = 0.f;
        unsigned pk[4];
        float4 ff[4] = {f0,f1,f2,f3};
#pragma unroll
        for(int u=0;u<4;u++){
          int q0=(int)rintf(ff[u].x*s), q1=(int)rintf(ff[u].y*s);
          int q2=(int)rintf(ff[u].z*s), q3=(int)rintf(ff[u].w*s);
          float d0=ff[u].x-(float)q0*invs, d1=ff[u].y-(float)q1*invs;
          float d2=ff[u].z-(float)q2*invs, d3=ff[u].w-(float)q3*invs;
          rsq=fmaf(d0,d0,rsq); rsq=fmaf(d1,d1,rsq);
          rsq=fmaf(d2,d2,rsq); rsq=fmaf(d3,d3,rsq);
          pk[u] = ((unsigned)(q0&255)) | ((unsigned)(q1&255)<<8)
                | ((unsigned)(q2&255)<<16) | ((unsigned)(q3&255)<<24);
        }
        uint4 qq; qq.x=pk[0]; qq.y=pk[1]; qq.z=pk[2]; qq.w=pk[3];
        qtab[j*64 + lane] = qq;
        rsq = wredsum(rsq);
        if(lane==0){
          qrho[j] = sqrtf(rsq)*1.0002f + 1e-8f;
          qinv[j] = invs;
        }
      }
    }
  }
  __syncthreads();
  {
    float rv = (tid<LROWS) ? qrho[tid] : 0.f;
    if(tid<128){
      float m = wredmax(rv);
      if(lane==0) wred2[w]=m;
    }
  }
  __syncthreads();
  if(tid==0) rhomax_sh = fmaxf(wred2[0], wred2[1]);

  // ---- wid0 = argmax(W_li . hs + b_li)  (round-1 verbatim) ----
  {
    float bestv=-FLT_MAX; int besti=0;
    for(int j=w; j<LROWS; j+=NWAVES){
      const int r = b*LROWS + j;
      float s = wredsum(partdot(W_li + (size_t)r*H, hbuf[0], lane));
      if(lane==0){
        float v = s + b_li[r];
        if(v>bestv){ bestv=v; besti=r; }
      }
    }
    if(lane==0){ redv[w]=bestv; redi[w]=besti; }
    __syncthreads();
    if(tid==0){
      float bv=redv[0]; int bi=redi[0];
      for(int i=1;i<NWAVES;i++)
        if(redv[i]>bv || (redv[i]==bv && redi[i]<bi)){ bv=redv[i]; bi=redi[i]; }
      cstore(&pval[b], bv); cstorei(&pidx[b], bi);
    }
  }
  GRID_BARRIER();
  {
    GARGMAX();
    __syncthreads();
    if(tid==0){
      float bv=redv[0]; int bi=redi[0];
      for(int i=1;i<4;i++)
        if(redv[i]>bv || (redv[i]==bv && redi[i]<bi)){ bv=redv[i]; bi=redi[i]; }
      wid_sh = bi;
      done_sh = (bi==EOS_ID) ? 1 : 0;
    }
    __syncthreads();
  }

  // ---- first decoder cell ----
  {
    const int row = b*GROWS + w;
    const float* tk = embed_target + (size_t)wid_sh*H;
    float s = partdot(W_ih_d + (size_t)row*H, tk, lane)
            + partdot(W_hh_d + (size_t)row*H, hbuf[0], lane);
    s = wredsum(s);
    if(lane==0) cstore(&gatesA[row], s + b_ih_d[row] + b_hh_d[row]);
  }
  GRID_BARRIER();
  {
    const int d = tid;
    float gi=cload(&gatesA[d]), gf=cload(&gatesA[d+H]),
          gg=cload(&gatesA[d+2*H]), go=cload(&gatesA[d+3*H]);
    float ii=sigm(gi), ff=sigm(gf), g2=tanhf(gg), oo=sigm(go);
    float c2=fmaf(ff, c_lds[d], ii*g2);
    c_lds[d]=c2;
    hbuf[1][d]=oo*tanhf(c2);
  }
  __syncthreads();
  if(b<SLEN && w==0){
    float s = wredsum(partdot(hsrow, hbuf[1], lane));
    if(lane==0) cstore(&scoresg[b], s);
  }
  {
    const int row=b*GROWS+w;
    float s=wredsum(partdot(W_hh_d + (size_t)row*H, hbuf[1], lane));
    if(lane==0) gwhh_l[w]=s;
  }
  GRID_BARRIER();

  // ---- decode: 51 steps, 2 grid barriers each ----
  int cur = 1;
  for(int k=0;k<NSTEP;k++){
    float* hk = hbuf[cur];
    float* hn = hbuf[cur^1];
    // -------- P1 --------
    if(k>0){
      GARGMAX();
      __syncthreads();
      if(tid==0){
        float bv=redv[0]; int bi=redi[0];
        for(int i=1;i<4;i++)
          if(redv[i]>bv || (redv[i]==bv && redi[i]<bi)){ bv=redv[i]; bi=redi[i]; }
        int iseos=(bi==EOS_ID)?1:0;
        if(b==0) out[k-1]=(float)((done_sh|iseos)?-1:bi);
        done_sh |= iseos;
        wid_sh = bi;
      }
      __syncthreads();
    }
    // softmax over 128 scores (e written back into sraw)
    if(tid<SLEN) sraw[tid]=cload(&scoresg[tid]);
    __syncthreads();
    if(tid<SLEN){
      float m = wredmax(sraw[tid]);
      if(lane==0) wred2[w]=m;
    }
    __syncthreads();
    if(tid<SLEN){
      float mx=fmaxf(wred2[0],wred2[1]);
      float e=expf(sraw[tid]-mx);
      sraw[tid]=e;
      float z=wredsum(e);
      if(lane==0) wred2[2+w]=z;
    }
    __syncthreads();
    // decoder LSTM gates
    {
      const int row=b*GROWS+w;
      const float* tk=embed_target + (size_t)wid_sh*H;
      float s=wredsum(partdot(W_ih_d + (size_t)row*H, tk, lane));
      if(lane==0) cstore(&gatesA[row], s + gwhh_l[w] + b_ih_d[row] + b_hh_d[row]);
    }
    // ht_new rows via M-trick
    if(w<HROWS){
      const int r=b*HROWS+w;
      float invZ=1.f/(wred2[2]+wred2[3]);
      float att=fmaf(sraw[2*lane],Mloc[w][2*lane], sraw[2*lane+1]*Mloc[w][2*lane+1]);
      float s=partdot(W_tl + (size_t)r*2*H + H, hk, lane);
      float tot=wredsum(fmaf(att,invZ,s));
      if(lane==0) cstore(&htng[r], tanhf(tot + b_tl[r]));
    }
    GRID_BARRIER();
    // -------- P2 --------
    {
      htn_lds[tid]=cload(&htng[tid]);
      const int d=tid;
      float gi=cload(&gatesA[d]), gf=cload(&gatesA[d+H]),
            gg=cload(&gatesA[d+2*H]), go=cload(&gatesA[d+3*H]);
      float ii=sigm(gi), ff=sigm(gf), g2=tanhf(gg), oo=sigm(go);
      float c2=fmaf(ff,c_lds[d],ii*g2);
      c_lds[d]=c2;
      hn[d]=oo*tanhf(c2);
    }
    __syncthreads();
    // ||h||^2 partials; reset rescue counter
    {
      float x = htn_lds[tid];
      float ss = wredsum(x*x);
      if(lane==0) hn2[w]=ss;
      if(tid==0) rcnt_sh=0;
    }
    __syncthreads();              // S1
    if(tid==0){
      float t2=0.f;
      for(int i=0;i<NWAVES;i++) t2+=hn2[i];
      float e = rhomax_sh * sqrtf(t2) * 1.0002f + 2e-3f;
      if(!(e>0.f && e<1e6f)) e=3.0e38f;   // degenerate -> screen everything
      e_sh = e;
    }
    // int8 screening matvec from LDS (zero global traffic)
    {
      const float4* h4=(const float4*)htn_lds;
      float4 h0=h4[4*lane], h1=h4[4*lane+1], h2=h4[4*lane+2], h3=h4[4*lane+3];
      const int rbase=b*LROWS;
#pragma unroll
      for(int t=0;t<8;t++){
        const int j=w+NWAVES*t;
        if(j<LROWS){
          uint4 q = qtab[j*64 + lane];
          float acc=0.f;
          acc=dotq(q.x,h0,acc); acc=dotq(q.y,h1,acc);
          acc=dotq(q.z,h2,acc); acc=dotq(q.w,h3,acc);
          acc=wredsum(acc);
          if(lane==0) vloc[j] = acc*qinv[j] + b_lt[rbase+j];
        }
      }
    }
    __syncthreads();              // S2: vloc + e_sh visible
    // approx logits out (error << 629 threshold) + block max of v-hat
    {
      const size_t obase = TOKS_OFF + (size_t)k*VOUT + (size_t)b*LROWS;
      if(tid<LROWS) out[obase+tid]=vloc[tid];
      float mv=(tid<LROWS)?vloc[tid]:-FLT_MAX;
      if(tid<128){
        float m=wredmax(mv);
        if(lane==0) wred2[w]=m;
      }
    }
    __syncthreads();              // S3
    {
      float thr = fmaxf(wred2[0],wred2[1]) - 2.0f*e_sh;
      if(tid<LROWS && vloc[tid]>=thr){
        int pos=atomicAdd(&rcnt_sh,1);
        rlist[pos]=tid;
      }
    }
    __syncthreads();              // S4: rlist ready
    // exact fp32 re-dot of screened rows (round-1-identical arithmetic)
    {
      float bestv=-FLT_MAX; int besti=0x7fffffff;
      const int nr=rcnt_sh;
      for(int s2=w;s2<nr;s2+=NWAVES){
        const int r=b*LROWS+rlist[s2];
        float s=wredsum(partdot(W_lt + (size_t)r*H, htn_lds, lane));
        if(lane==0){
          float f=s+b_lt[r];
          if(f>bestv || (f==bestv && r<besti)){ bestv=f; besti=r; }
        }
      }
      if(lane==0){ redv[w]=bestv; redi[w]=besti; }
    }
    if(b<SLEN && w==0){
      float s=wredsum(partdot(hsrow, hn, lane));
      if(lane==0) cstore(&scoresg[b], s);
    }
    {
      const int row=b*GROWS+w;
      float s=wredsum(partdot(W_hh_d + (size_t)row*H, hn, lane));
      if(lane==0) gwhh_l[w]=s;
    }
    __syncthreads();              // S5
    if(tid==0){
      float bv=redv[0]; int bi=redi[0];
      for(int i=1;i<NWAVES;i++)
        if(redv[i]>bv || (redv[i]==bv && redi[i]<bi)){ bv=redv[i]; bi=redi[i]; }
      cstore(&pval[b], bv); cstorei(&pidx[b], bi);
    }
    GRID_BARRIER();
    cur ^= 1;
  }

  // ---- epilogue: last token ----
  if(b==0){
    GARGMAX();
    __syncthreads();
    if(tid==0){
      float bv=redv[0]; int bi=redi[0];
      for(int i=1;i<4;i++)
        if(redv[i]>bv || (redv[i]==bv && redi[i]<bi)){ bv=redv[i]; bi=redi[i]; }
      int iseos=(bi==EOS_ID)?1:0;
      out[NSTEP-1]=(float)((done_sh|iseos)?-1:bi);
    }
  }
#undef GARGMAX
#undef GRID_BARRIER
}

extern "C" void kernel_launch(void* const* d_in, const int* in_sizes, int n_in,
                              void* d_out, int out_size, void* d_ws, size_t ws_size,
                              hipStream_t stream) {
  const int*   src_ids      = (const int*)  d_in[0];
  const float* embed_input  = (const float*)d_in[1];
  const float* W_ih_e       = (const float*)d_in[2];
  const float* W_hh_e       = (const float*)d_in[3];
  const float* b_ih_e       = (const float*)d_in[4];
  const float* b_hh_e       = (const float*)d_in[5];
  const float* W_li         = (const float*)d_in[6];
  const float* b_li         = (const float*)d_in[7];
  const float* embed_target = (const float*)d_in[8];
  const float* W_ih_d       = (const float*)d_in[9];
  const float* W_hh_d       = (const float*)d_in[10];
  const float* b_ih_d       = (const float*)d_in[11];
  const float* b_hh_d       = (const float*)d_in[12];
  const float* W_lt         = (const float*)d_in[13];
  const float* b_lt         = (const float*)d_in[14];
  const float* W_tl         = (const float*)d_in[15];
  const float* b_tl         = (const float*)d_in[16];
  float*       out          = (float*)d_out;
  unsigned*    counters     = (unsigned*)d_ws;
  float*       wsf          = (float*)d_ws + 1024;   // data after 4KB counter area

  // zero the barrier counters every launch (graph-capture-safe)
  hipMemsetAsync(d_ws, 0, 4096, stream);

  void* args[] = {
    (void*)&src_ids, (void*)&embed_input,
    (void*)&W_ih_e, (void*)&W_hh_e, (void*)&b_ih_e, (void*)&b_hh_e,
    (void*)&W_li, (void*)&b_li, (void*)&embed_target,
    (void*)&W_ih_d, (void*)&W_hh_d, (void*)&b_ih_d, (void*)&b_hh_d,
    (void*)&W_lt, (void*)&b_lt, (void*)&W_tl, (void*)&b_tl,
    (void*)&out, (void*)&wsf, (void*)&counters
  };

  hipError_t err = hipLaunchCooperativeKernel((const void*)nmt_kernel,
                                              dim3(NB), dim3(BT), args,
                                              QTAB_BYTES, stream);
  if (err != hipSuccess) {
    // fallback: plain launch; 256 blocks x 1024 threads -> 1 block/CU, co-resident
    nmt_kernel<<<dim3(NB), dim3(BT), QTAB_BYTES, stream>>>(
        src_ids, embed_input, W_ih_e, W_hh_e, b_ih_e, b_hh_e,
        W_li, b_li, embed_target, W_ih_d, W_hh_d, b_ih_d, b_hh_d,
        W_lt, b_lt, W_tl, b_tl, out, wsf, counters);
  }
}